// Round 19
// baseline (48.771 us; speedup 1.0000x reference)
//
#include <hip/hip_runtime.h>

typedef _Float16 f16x8 __attribute__((ext_vector_type(8)));
typedef float f32x4 __attribute__((ext_vector_type(4)));
typedef unsigned int u32x2 __attribute__((ext_vector_type(2)));

#define MROWS 65536
#define BM 64             // rows per block (4 waves)
#define NBLK (MROWS / BM) // 1024

// ---- d_ws byte offsets ----
#define B1F_OFF 0u       // GEMM1 B frags: [2kt][16nt][64lane][8] f16 = 32768 B (K=64)
#define B2F_OFF 65536u   // GEMM2 B frags: [8kt][16nt][64lane][8] f16 = 131072 B
#define TP_OFF 196608u   // phone_table @ W1[64:192]: [100][256] f32
#define TM_OFF 299008u   // midi_table @ W1[192:256]: [128][256] f32
#define BC_OFF 430080u   // fused bias: [256] f32
// (Wfd never materialized: B1 fragments are computed inline in prep_all)

// Fragment k-slot mapping (all A and B fragments):
//   k = kt*32 + 4*(lane>>4) + (e&3) + 16*(e>>2)
// B fragments use a PERMUTED column layout: tile nt, lane c holds logical
// column (nt>>2)*64 + c*4 + (nt&3).
// C/D: col_tile = lane&15 (permuted); row = (lane>>4)*4 + reg.
// P granule (64-row tile): X = (kt*4 + it)*64 + (row&15) + 16*(c&3),
// byte half = 8*((c>>2)&1), kt = 2*g + (c>>3)   [verified rounds 5-18].
//
// ROUND-19: main kernel = round-12 VERBATIM (best measured: 37.8us wall; 7
// structural variants since all neutral or spilled). Single isolated change:
// the serial 3-launch chain (prep_tables -> prep_frags -> main) becomes a
// 2-launch chain. prep_frags' dependency on materialized Wfd is removed by
// computing each B1 fragment element's dot-64 inline (16K threads x 64 fmaf).
// B2 frags: 1 elem/thread uniform copy (round-15's lopsided merge avoided).
// Spill signature on main (unchanged code, sanity): FETCH >> 3 MB.

// P-buffer swizzle: XOR addr bits [4:5] with X bits [4:5].
__device__ __forceinline__ unsigned a2off(unsigned X) {
  return (X * 16u) ^ (X & 0x30u);
}

// ---- single prep kernel: 309 blocks x 1024 threads ----
// r 0..99    : Tp row r        (4-way K-split reduce; identical to round 12)
// r 100..227 : Tm row (r-100)  (4-way K-split reduce)
// r 228      : fused bias BC   (4-way K-split reduce)
// r 229..244 : B1 frags, 1 elem/thread, Wfd dot-64 computed inline
// r 245..308 : B2 frags, 1 elem/thread, permuted copy of W2
__global__ __launch_bounds__(1024) void prep_all(
    const float* __restrict__ f0_w2, const float* __restrict__ f0_b2,
    const float* __restrict__ ptab, const float* __restrict__ mtab,
    const float* __restrict__ dur_w2, const float* __restrict__ dur_b2,
    const float* __restrict__ W1, const float* __restrict__ pb1,
    const float* __restrict__ W2, char* __restrict__ ws) {
  __shared__ float red[4][256];
  const int r = blockIdx.x;
  const int tid = threadIdx.x;
  float* wsf = (float*)ws;

  if (r < 229) {  // table rows, 4-way K-split (round-12 path, re-indexed)
    const int n = tid & 255;
    const int ks = tid >> 8;  // 0..3
    float s = 0.f;
    if (r < 100) {  // Tp row: K=128 -> 32/ks
      for (int j = ks * 32; j < ks * 32 + 32; ++j)
        s = fmaf(ptab[r * 128 + j], W1[(64 + j) * 256 + n], s);
    } else if (r < 228) {  // Tm row: K=64 -> 16/ks
      const int m = r - 100;
      for (int j = ks * 16; j < ks * 16 + 16; ++j)
        s = fmaf(mtab[m * 64 + j], W1[(192 + j) * 256 + n], s);
    } else {  // fused bias: two K=64 loops -> 16/ks each
      for (int j = ks * 16; j < ks * 16 + 16; ++j) {
        s = fmaf(f0_b2[j], W1[j * 256 + n], s);
        s = fmaf(dur_b2[j], W1[(256 + j) * 256 + n], s);
      }
    }
    red[ks][n] = s;
    __syncthreads();
    if (ks == 0) {
      const float t = red[0][n] + red[1][n] + red[2][n] + red[3][n];
      if (r < 100) wsf[TP_OFF / 4 + r * 256 + n] = t;
      else if (r < 228) wsf[TM_OFF / 4 + (r - 100) * 256 + n] = t;
      else wsf[BC_OFF / 4 + n] = t + pb1[n];
    }
  } else if (r < 245) {  // B1 frag elements: idx in [0, 32*512)
    const int idx = (r - 229) * 1024 + tid;
    const int t = idx >> 9;          // tile 0..31
    const int within = idx & 511;
    const int l = within & 63, e = within >> 6;  // lane, elem
    const int kt = t >> 4, nt = t & 15;
    const int qq = l >> 4, c = l & 15;
    const int col = (nt >> 2) * 64 + c * 4 + (nt & 3);  // permuted column
    const int k = kt * 32 + 4 * qq + (e & 3) + 16 * (e >> 2);  // 0..63
    float s = 0.f;
    if (k < 32) {
      for (int j = 0; j < 64; ++j) s = fmaf(f0_w2[k * 64 + j], W1[j * 256 + col], s);
    } else {
      for (int j = 0; j < 64; ++j) s = fmaf(dur_w2[(k - 32) * 64 + j], W1[(256 + j) * 256 + col], s);
    }
    *(_Float16*)(ws + B1F_OFF + (unsigned)((kt * 16 + nt) * 64 + l) * 16u + (unsigned)e * 2u) =
        (_Float16)s;
  } else {  // B2 frag elements: idx in [0, 128*512)
    const int idx = (r - 245) * 1024 + tid;
    const int t2 = idx >> 9;         // tile 0..127
    const int within = idx & 511;
    const int l = within & 63, e = within >> 6;
    const int kt = t2 >> 4, nt = t2 & 15;
    const int qq = l >> 4, c = l & 15;
    const int col = (nt >> 2) * 64 + c * 4 + (nt & 3);  // permuted column
    const int k = kt * 32 + 4 * qq + (e & 3) + 16 * (e >> 2);
    *(_Float16*)(ws + B2F_OFF + (unsigned)((kt * 16 + nt) * 64 + l) * 16u + (unsigned)e * 2u) =
        (_Float16)W2[k * 256 + col];
  }
}

// Main kernel (round-12 verbatim): 4 waves, 64 rows/block; phase split:
//   GEMM1/epilogue: wave (wi,wh) -> rows wi*32..+32, cols wh*128..+128
//   GEMM2/store:    wave w       -> all 64 rows, cols w*64..+64
__global__ __launch_bounds__(256, 3) void cond_enc_main(
    const float* __restrict__ f0g, const int* __restrict__ phone,
    const float* __restrict__ durg, const int* __restrict__ midi,
    const float* __restrict__ f0_w1, const float* __restrict__ f0_b1,
    const float* __restrict__ dur_w1, const float* __restrict__ dur_b1,
    const float* __restrict__ ln_g, const float* __restrict__ ln_b,
    const float* __restrict__ pb2, const char* __restrict__ ws,
    float* __restrict__ out) {
  // LDS: P buffer (32 frags x 1KB, swizzled) + LN partials [64][4]
  __shared__ __align__(16) unsigned char smem[32768 + 1024];
  unsigned char* Pbuf = smem;
  float* partials = (float*)(smem + 32768);

  const int tid = threadIdx.x;
  const int l = tid & 63;
  const int w = tid >> 6;   // wave 0..3
  const int wi = w & 1;     // GEMM1: row half (32 rows)
  const int wh = w >> 1;    // GEMM1: column half (128 cols)
  const int q = l >> 4;     // 0..3
  const int c = l & 15;     // 0..15
  const int rowbase = blockIdx.x * BM;

  const float* Tp = (const float*)(ws + TP_OFF);
  const float* Tm = (const float*)(ws + TM_OFF);

  // one coalesced load per lane (lane l covers block row l); idx loads first
  // (they feed the longest chain: idx -> shfl -> gather -> LN)
  const int ph_all = phone[rowbase + l];
  const int md_all = midi[rowbase + l];
  const float xf_all = f0g[rowbase + l];
  const float xd_all = durg[rowbase + l];

  // ---- A1 fragments for this wave's 32 rows (K=64: kt0=f0, kt1=dur) ----
  f16x8 a1[2][2];  // [i row-tile][kt] = 16 regs
#pragma unroll
  for (int i = 0; i < 2; ++i) {
    const float xf = __shfl(xf_all, wi * 32 + i * 16 + c);
    const float xd = __shfl(xd_all, wi * 32 + i * 16 + c);
#pragma unroll
    for (int kh = 0; kh < 2; ++kh) {
      f16x8 v;
#pragma unroll
      for (int e = 0; e < 8; ++e) {
        const int ki = 4 * q + (e & 3) + 16 * (e >> 2);  // 0..31
        const float wv = kh ? dur_w1[ki] : f0_w1[ki];
        const float bv = kh ? dur_b1[ki] : f0_b1[ki];
        const float x = kh ? xd : xf;
        v[e] = (_Float16)fmaxf(fmaf(x, wv, bv), 0.f);
      }
      a1[i][kh] = v;
    }
  }

  // ---- GEMM1 (K=64): 32 rows x 128 cols -> acc1[2][8] = 64 regs ----
  const f32x4 zero4 = {0.f, 0.f, 0.f, 0.f};
  f32x4 acc1[2][8];
#pragma unroll
  for (int i = 0; i < 2; ++i)
#pragma unroll
    for (int j = 0; j < 8; ++j) acc1[i][j] = zero4;
  {
    const f16x8* B1p = (const f16x8*)(ws + B1F_OFF);
#pragma unroll
    for (int kt = 0; kt < 2; ++kt) {
#pragma unroll
      for (int jc = 0; jc < 2; ++jc) {  // 4-tile chunks
        f16x8 bfr[4];
#pragma unroll
        for (int j = 0; j < 4; ++j) bfr[j] = B1p[(kt * 16 + wh * 8 + jc * 4 + j) * 64 + l];
#pragma unroll
        for (int i = 0; i < 2; ++i)
#pragma unroll
          for (int j = 0; j < 4; ++j)
            acc1[i][jc * 4 + j] =
                __builtin_amdgcn_mfma_f32_16x16x32_f16(a1[i][kt], bfr[j], acc1[i][jc * 4 + j], 0, 0, 0);
      }
    }
  }

  // ---- epilogue: += bias + Tp[phone] + Tm[midi]; half-row LN partials ----
  const float* bcp = (const float*)(ws + BC_OFF);
#pragma unroll
  for (int i = 0; i < 2; ++i) {
#pragma unroll
    for (int r = 0; r < 4; ++r) {
      const int rrel = wi * 32 + i * 16 + q * 4 + r;  // block-relative row
      const int ph = __shfl(ph_all, rrel);
      const int md = __shfl(md_all, rrel);
      float s = 0.f, ss = 0.f;
#pragma unroll
      for (int gl = 0; gl < 2; ++gl) {
        const int g = wh * 2 + gl;
        const f32x4 tp4 = *(const f32x4*)(Tp + ph * 256 + g * 64 + c * 4);
        const f32x4 tm4 = *(const f32x4*)(Tm + md * 256 + g * 64 + c * 4);
        const f32x4 bc4 = *(const f32x4*)(bcp + g * 64 + c * 4);
#pragma unroll
        for (int bq = 0; bq < 4; ++bq) {
          float v = acc1[i][4 * gl + bq][r] + bc4[bq] + tp4[bq] + tm4[bq];
          acc1[i][4 * gl + bq][r] = v;
          s += v;
          ss = fmaf(v, v, ss);
        }
      }
#pragma unroll
      for (int m = 1; m < 16; m <<= 1) {  // reduce this wave's 128-col half
        s += __shfl_xor(s, m, 64);
        ss += __shfl_xor(ss, m, 64);
      }
      if (c == 0) {
        partials[rrel * 4 + wh * 2 + 0] = s;
        partials[rrel * 4 + wh * 2 + 1] = ss;
      }
    }
  }
  __syncthreads();

  // ---- LN (per lane) + ReLU + pack this wave's quadrant into shared P ----
  const int lp_base = 16 * (c & 3);
  const unsigned hoff = (unsigned)((c >> 2) & 1) * 8u;
#pragma unroll
  for (int i = 0; i < 2; ++i) {
#pragma unroll
    for (int r = 0; r < 4; ++r) {
      const int rrel = wi * 32 + i * 16 + q * 4 + r;
      const int it = wi * 2 + i;  // 16-row tile index 0..3
      const f32x4 pr = *(const f32x4*)(partials + rrel * 4);
      const float s = pr[0] + pr[2];
      const float ss = pr[1] + pr[3];
      const float mu = s * (1.f / 256.f);
      const float var = fmaxf(ss * (1.f / 256.f) - mu * mu, 0.f);
      const float rstd = rsqrtf(var + 1e-5f);
#pragma unroll
      for (int gl = 0; gl < 2; ++gl) {
        const int g = wh * 2 + gl;
        const f32x4 g4 = *(const f32x4*)(ln_g + g * 64 + c * 4);
        const f32x4 lb4 = *(const f32x4*)(ln_b + g * 64 + c * 4);
        unsigned short hw[4];
#pragma unroll
        for (int bq = 0; bq < 4; ++bq) {
          float v = fmaf((acc1[i][4 * gl + bq][r] - mu) * rstd, g4[bq], lb4[bq]);
          v = fmaxf(v, 0.f);
          hw[bq] = __builtin_bit_cast(unsigned short, (_Float16)v);
        }
        u32x2 pkt;
        pkt[0] = (unsigned)hw[0] | ((unsigned)hw[1] << 16);
        pkt[1] = (unsigned)hw[2] | ((unsigned)hw[3] << 16);
        const int kt = 2 * g + (c >> 3);
        const unsigned X = (unsigned)((kt * 4 + it) * 64 + (q * 4 + r + lp_base));
        *(u32x2*)(Pbuf + a2off(X) + hoff) = pkt;
      }
    }
  }
  __syncthreads();

  // ---- GEMM2 (K=256): 64 rows x 64 cols (nt = w*4+j) -> acc2[4][4] = 64 regs ----
  f32x4 acc2[4][4];
#pragma unroll
  for (int it = 0; it < 4; ++it)
#pragma unroll
    for (int j = 0; j < 4; ++j) acc2[it][j] = zero4;
  {
    const f16x8* B2p = (const f16x8*)(ws + B2F_OFF);
#pragma unroll
    for (int kt = 0; kt < 8; ++kt) {
      f16x8 av[4], bfr[4];
#pragma unroll
      for (int it = 0; it < 4; ++it)
        av[it] = *(const f16x8*)(Pbuf + a2off((unsigned)((kt * 4 + it) * 64 + l)));
#pragma unroll
      for (int j = 0; j < 4; ++j) bfr[j] = B2p[(kt * 16 + w * 4 + j) * 64 + l];
#pragma unroll
      for (int it = 0; it < 4; ++it)
#pragma unroll
        for (int j = 0; j < 4; ++j)
          acc2[it][j] = __builtin_amdgcn_mfma_f32_16x16x32_f16(av[it], bfr[j], acc2[it][j], 0, 0, 0);
    }
  }

  // ---- store: 64 rows x 64 cols (cols w*64 + c*4 + j), float4 nt-stores ----
  const f32x4 b24 = *(const f32x4*)(pb2 + w * 64 + c * 4);
#pragma unroll
  for (int it = 0; it < 4; ++it)
#pragma unroll
    for (int r = 0; r < 4; ++r) {
      const int grow = rowbase + it * 16 + q * 4 + r;
      f32x4 st;
#pragma unroll
      for (int j = 0; j < 4; ++j) st[j] = acc2[it][j][r] + b24[j];
      __builtin_nontemporal_store(st, (f32x4*)(out + grow * 256 + w * 64 + c * 4));
    }
}

extern "C" void kernel_launch(void* const* d_in, const int* in_sizes, int n_in,
                              void* d_out, int out_size, void* d_ws, size_t ws_size,
                              hipStream_t stream) {
  (void)in_sizes; (void)n_in; (void)out_size; (void)ws_size;
  const float* f0 = (const float*)d_in[0];
  const int* phone = (const int*)d_in[1];
  const float* dur = (const float*)d_in[2];
  const int* midi = (const int*)d_in[3];
  const float* f0_w1 = (const float*)d_in[4];
  const float* f0_b1 = (const float*)d_in[5];
  const float* f0_w2 = (const float*)d_in[6];
  const float* f0_b2 = (const float*)d_in[7];
  const float* ptab = (const float*)d_in[8];
  const float* mtab = (const float*)d_in[9];
  const float* dur_w1 = (const float*)d_in[10];
  const float* dur_b1 = (const float*)d_in[11];
  const float* dur_w2 = (const float*)d_in[12];
  const float* dur_b2 = (const float*)d_in[13];
  const float* W1 = (const float*)d_in[14];
  const float* pb1 = (const float*)d_in[15];
  const float* ln_g = (const float*)d_in[16];
  const float* ln_b = (const float*)d_in[17];
  const float* W2 = (const float*)d_in[18];
  const float* pb2 = (const float*)d_in[19];
  char* ws = (char*)d_ws;
  float* out = (float*)d_out;

  prep_all<<<309, 1024, 0, stream>>>(f0_w2, f0_b2, ptab, mtab, dur_w2, dur_b2, W1, pb1, W2, ws);
  cond_enc_main<<<NBLK, 256, 0, stream>>>(f0, phone, dur, midi, f0_w1, f0_b1, dur_w1, dur_b1,
                                          ln_g, ln_b, pb2, ws, out);
}

// Round 20
// 37.916 us; speedup vs baseline: 1.2863x; 1.2863x over previous
//
#include <hip/hip_runtime.h>

typedef _Float16 f16x8 __attribute__((ext_vector_type(8)));
typedef float f32x4 __attribute__((ext_vector_type(4)));
typedef unsigned int u32x2 __attribute__((ext_vector_type(2)));

#define MROWS 65536
#define BM 64             // rows per block (4 waves)
#define NBLK (MROWS / BM) // 1024

// ---- d_ws byte offsets ----
#define B1F_OFF 0u       // GEMM1 B frags: [2kt][16nt][64lane][8] f16 = 32768 B (K=64)
#define B2F_OFF 65536u   // GEMM2 B frags: [8kt][16nt][64lane][8] f16 = 131072 B
#define TP_OFF 196608u   // phone_table @ W1[64:192]: [100][256] f32
#define TM_OFF 299008u   // midi_table @ W1[192:256]: [128][256] f32
#define BC_OFF 430080u   // fused bias: [256] f32
#define WFD_OFF 431104u  // fused f0/dur weights: [64][256] f32 (ends 496640)

// Fragment k-slot mapping (all A and B fragments):
//   k = kt*32 + 4*(lane>>4) + (e&3) + 16*(e>>2)
// B fragments use a PERMUTED column layout: tile nt, lane c holds logical
// column (nt>>2)*64 + c*4 + (nt&3).
// C/D: col_tile = lane&15 (permuted); row = (lane>>4)*4 + reg.
// P granule (64-row tile): X = (kt*4 + it)*64 + (row&15) + 16*(c&3),
// byte half = 8*((c>>2)&1), kt = 2*g + (c>>3)   [verified rounds 5-19].
//
// FINAL (round-20): round-12 VERBATIM — the measured optimum of this design
// space (wall 37.8us). Rounds 13-19 tested: GEMM2 half-split (-), f16 tables
// (0), 2-tile pipelines x2 (spill), plain stores (0/-), prep merges x2 (-),
// BM=32 phase-split recombination (0). The main kernel is latency-structured
// at ~31us with nothing saturated; every structural lever under the (256,3)
// register budget is exhausted. Key locked-in lessons:
//  * (256,3) cap (~170 regs) is the only budget that fits this body; any
//    added live state (loop restructure, prefetch, caps of 128) spills with
//    signature FETCH>>3MB / WRITE>>66MB.
//  * nt-stores == plain stores here; traffic halving and occupancy doubling
//    both neutral; per-block latency chain is the floor.

// P-buffer swizzle: XOR addr bits [4:5] with X bits [4:5].
__device__ __forceinline__ unsigned a2off(unsigned X) {
  return (X * 16u) ^ (X & 0x30u);
}

// prep_tables with 4-way K-split (1024 thr).
__global__ __launch_bounds__(1024) void prep_tables(
    const float* __restrict__ f0_w2, const float* __restrict__ f0_b2,
    const float* __restrict__ ptab, const float* __restrict__ mtab,
    const float* __restrict__ dur_w2, const float* __restrict__ dur_b2,
    const float* __restrict__ W1, const float* __restrict__ pb1,
    float* __restrict__ wsf) {
  __shared__ float red[4][256];
  const int r = blockIdx.x;
  const int n = threadIdx.x & 255;
  const int ks = threadIdx.x >> 8;  // 0..3
  float s = 0.f;
  if (r < 64) {  // Wfd row r: K=64 -> 16/ks
    if (r < 32) {
      for (int j = ks * 16; j < ks * 16 + 16; ++j) s = fmaf(f0_w2[r * 64 + j], W1[j * 256 + n], s);
    } else {
      for (int j = ks * 16; j < ks * 16 + 16; ++j)
        s = fmaf(dur_w2[(r - 32) * 64 + j], W1[(256 + j) * 256 + n], s);
    }
  } else if (r < 164) {  // Tp row: K=128 -> 32/ks
    const int p = r - 64;
    for (int j = ks * 32; j < ks * 32 + 32; ++j) s = fmaf(ptab[p * 128 + j], W1[(64 + j) * 256 + n], s);
  } else if (r < 292) {  // Tm row: K=64 -> 16/ks
    const int m = r - 164;
    for (int j = ks * 16; j < ks * 16 + 16; ++j) s = fmaf(mtab[m * 64 + j], W1[(192 + j) * 256 + n], s);
  } else {  // fused bias: two K=64 loops -> 16/ks each
    for (int j = ks * 16; j < ks * 16 + 16; ++j) {
      s = fmaf(f0_b2[j], W1[j * 256 + n], s);
      s = fmaf(dur_b2[j], W1[(256 + j) * 256 + n], s);
    }
  }
  red[ks][n] = s;
  __syncthreads();
  if (ks == 0) {
    float t = red[0][n] + red[1][n] + red[2][n] + red[3][n];
    if (r < 64) wsf[WFD_OFF / 4 + r * 256 + n] = t;
    else if (r < 164) wsf[TP_OFF / 4 + (r - 64) * 256 + n] = t;
    else if (r < 292) wsf[TM_OFF / 4 + (r - 164) * 256 + n] = t;
    else wsf[BC_OFF / 4 + n] = t + pb1[n];
  }
}

__global__ __launch_bounds__(64) void prep_frags(const float* __restrict__ W2, char* __restrict__ ws) {
  const float* Wfd = (const float*)(ws + WFD_OFF);
  const int t = blockIdx.x;
  const int l = threadIdx.x;
  const int qq = l >> 4, c = l & 15;
  if (t < 32) {  // B1: K=64
    const int kt = t >> 4, nt = t & 15;
    const int col = (nt >> 2) * 64 + c * 4 + (nt & 3);  // permuted column layout
    f16x8 v;
#pragma unroll
    for (int e = 0; e < 8; ++e) {
      const int k = kt * 32 + 4 * qq + (e & 3) + 16 * (e >> 2);
      v[e] = (_Float16)Wfd[k * 256 + col];
    }
    *(f16x8*)(ws + B1F_OFF + (unsigned)((kt * 16 + nt) * 64 + l) * 16u) = v;
  } else {  // B2 = proj_w2
    const int t2 = t - 32;
    const int kt = t2 >> 4, nt = t2 & 15;
    const int col = (nt >> 2) * 64 + c * 4 + (nt & 3);  // permuted column layout
    f16x8 v;
#pragma unroll
    for (int e = 0; e < 8; ++e) {
      const int k = kt * 32 + 4 * qq + (e & 3) + 16 * (e >> 2);
      v[e] = (_Float16)W2[k * 256 + col];
    }
    *(f16x8*)(ws + B2F_OFF + (unsigned)((kt * 16 + nt) * 64 + l) * 16u) = v;
  }
}

// Main kernel: 4 waves, 64 rows/block; phase-dependent work split:
//   GEMM1/epilogue: wave (wi,wh) -> rows wi*32..+32, cols wh*128..+128
//   GEMM2/store:    wave w       -> all 64 rows, cols w*64..+64
__global__ __launch_bounds__(256, 3) void cond_enc_main(
    const float* __restrict__ f0g, const int* __restrict__ phone,
    const float* __restrict__ durg, const int* __restrict__ midi,
    const float* __restrict__ f0_w1, const float* __restrict__ f0_b1,
    const float* __restrict__ dur_w1, const float* __restrict__ dur_b1,
    const float* __restrict__ ln_g, const float* __restrict__ ln_b,
    const float* __restrict__ pb2, const char* __restrict__ ws,
    float* __restrict__ out) {
  // LDS: P buffer (32 frags x 1KB, swizzled) + LN partials [64][4]
  __shared__ __align__(16) unsigned char smem[32768 + 1024];
  unsigned char* Pbuf = smem;
  float* partials = (float*)(smem + 32768);

  const int tid = threadIdx.x;
  const int l = tid & 63;
  const int w = tid >> 6;   // wave 0..3
  const int wi = w & 1;     // GEMM1: row half (32 rows)
  const int wh = w >> 1;    // GEMM1: column half (128 cols)
  const int q = l >> 4;     // 0..3
  const int c = l & 15;     // 0..15
  const int rowbase = blockIdx.x * BM;

  const float* Tp = (const float*)(ws + TP_OFF);
  const float* Tm = (const float*)(ws + TM_OFF);

  // one coalesced load per lane (lane l covers block row l)
  const float xf_all = f0g[rowbase + l];
  const float xd_all = durg[rowbase + l];
  const int ph_all = phone[rowbase + l];
  const int md_all = midi[rowbase + l];

  // ---- A1 fragments for this wave's 32 rows (K=64: kt0=f0, kt1=dur) ----
  f16x8 a1[2][2];  // [i row-tile][kt] = 16 regs
#pragma unroll
  for (int i = 0; i < 2; ++i) {
    const float xf = __shfl(xf_all, wi * 32 + i * 16 + c);
    const float xd = __shfl(xd_all, wi * 32 + i * 16 + c);
#pragma unroll
    for (int kh = 0; kh < 2; ++kh) {
      f16x8 v;
#pragma unroll
      for (int e = 0; e < 8; ++e) {
        const int ki = 4 * q + (e & 3) + 16 * (e >> 2);  // 0..31
        const float wv = kh ? dur_w1[ki] : f0_w1[ki];
        const float bv = kh ? dur_b1[ki] : f0_b1[ki];
        const float x = kh ? xd : xf;
        v[e] = (_Float16)fmaxf(fmaf(x, wv, bv), 0.f);
      }
      a1[i][kh] = v;
    }
  }

  // ---- GEMM1 (K=64): 32 rows x 128 cols -> acc1[2][8] = 64 regs ----
  const f32x4 zero4 = {0.f, 0.f, 0.f, 0.f};
  f32x4 acc1[2][8];
#pragma unroll
  for (int i = 0; i < 2; ++i)
#pragma unroll
    for (int j = 0; j < 8; ++j) acc1[i][j] = zero4;
  {
    const f16x8* B1p = (const f16x8*)(ws + B1F_OFF);
#pragma unroll
    for (int kt = 0; kt < 2; ++kt) {
#pragma unroll
      for (int jc = 0; jc < 2; ++jc) {  // 4-tile chunks
        f16x8 bfr[4];
#pragma unroll
        for (int j = 0; j < 4; ++j) bfr[j] = B1p[(kt * 16 + wh * 8 + jc * 4 + j) * 64 + l];
#pragma unroll
        for (int i = 0; i < 2; ++i)
#pragma unroll
          for (int j = 0; j < 4; ++j)
            acc1[i][jc * 4 + j] =
                __builtin_amdgcn_mfma_f32_16x16x32_f16(a1[i][kt], bfr[j], acc1[i][jc * 4 + j], 0, 0, 0);
      }
    }
  }

  // ---- epilogue: += bias + Tp[phone] + Tm[midi]; half-row LN partials ----
  const float* bcp = (const float*)(ws + BC_OFF);
#pragma unroll
  for (int i = 0; i < 2; ++i) {
#pragma unroll
    for (int r = 0; r < 4; ++r) {
      const int rrel = wi * 32 + i * 16 + q * 4 + r;  // block-relative row
      const int ph = __shfl(ph_all, rrel);
      const int md = __shfl(md_all, rrel);
      float s = 0.f, ss = 0.f;
#pragma unroll
      for (int gl = 0; gl < 2; ++gl) {
        const int g = wh * 2 + gl;
        const f32x4 tp4 = *(const f32x4*)(Tp + ph * 256 + g * 64 + c * 4);
        const f32x4 tm4 = *(const f32x4*)(Tm + md * 256 + g * 64 + c * 4);
        const f32x4 bc4 = *(const f32x4*)(bcp + g * 64 + c * 4);
#pragma unroll
        for (int bq = 0; bq < 4; ++bq) {
          float v = acc1[i][4 * gl + bq][r] + bc4[bq] + tp4[bq] + tm4[bq];
          acc1[i][4 * gl + bq][r] = v;
          s += v;
          ss = fmaf(v, v, ss);
        }
      }
#pragma unroll
      for (int m = 1; m < 16; m <<= 1) {  // reduce this wave's 128-col half
        s += __shfl_xor(s, m, 64);
        ss += __shfl_xor(ss, m, 64);
      }
      if (c == 0) {
        partials[rrel * 4 + wh * 2 + 0] = s;
        partials[rrel * 4 + wh * 2 + 1] = ss;
      }
    }
  }
  __syncthreads();

  // ---- LN (per lane) + ReLU + pack this wave's quadrant into shared P ----
  const int lp_base = 16 * (c & 3);
  const unsigned hoff = (unsigned)((c >> 2) & 1) * 8u;
#pragma unroll
  for (int i = 0; i < 2; ++i) {
#pragma unroll
    for (int r = 0; r < 4; ++r) {
      const int rrel = wi * 32 + i * 16 + q * 4 + r;
      const int it = wi * 2 + i;  // 16-row tile index 0..3
      const f32x4 pr = *(const f32x4*)(partials + rrel * 4);
      const float s = pr[0] + pr[2];
      const float ss = pr[1] + pr[3];
      const float mu = s * (1.f / 256.f);
      const float var = fmaxf(ss * (1.f / 256.f) - mu * mu, 0.f);
      const float rstd = rsqrtf(var + 1e-5f);
#pragma unroll
      for (int gl = 0; gl < 2; ++gl) {
        const int g = wh * 2 + gl;
        const f32x4 g4 = *(const f32x4*)(ln_g + g * 64 + c * 4);
        const f32x4 lb4 = *(const f32x4*)(ln_b + g * 64 + c * 4);
        unsigned short hw[4];
#pragma unroll
        for (int bq = 0; bq < 4; ++bq) {
          float v = fmaf((acc1[i][4 * gl + bq][r] - mu) * rstd, g4[bq], lb4[bq]);
          v = fmaxf(v, 0.f);
          hw[bq] = __builtin_bit_cast(unsigned short, (_Float16)v);
        }
        u32x2 pkt;
        pkt[0] = (unsigned)hw[0] | ((unsigned)hw[1] << 16);
        pkt[1] = (unsigned)hw[2] | ((unsigned)hw[3] << 16);
        const int kt = 2 * g + (c >> 3);
        const unsigned X = (unsigned)((kt * 4 + it) * 64 + (q * 4 + r + lp_base));
        *(u32x2*)(Pbuf + a2off(X) + hoff) = pkt;
      }
    }
  }
  __syncthreads();

  // ---- GEMM2 (K=256): 64 rows x 64 cols (nt = w*4+j) -> acc2[4][4] = 64 regs ----
  f32x4 acc2[4][4];
#pragma unroll
  for (int it = 0; it < 4; ++it)
#pragma unroll
    for (int j = 0; j < 4; ++j) acc2[it][j] = zero4;
  {
    const f16x8* B2p = (const f16x8*)(ws + B2F_OFF);
#pragma unroll
    for (int kt = 0; kt < 8; ++kt) {
      f16x8 av[4], bfr[4];
#pragma unroll
      for (int it = 0; it < 4; ++it)
        av[it] = *(const f16x8*)(Pbuf + a2off((unsigned)((kt * 4 + it) * 64 + l)));
#pragma unroll
      for (int j = 0; j < 4; ++j) bfr[j] = B2p[(kt * 16 + w * 4 + j) * 64 + l];
#pragma unroll
      for (int it = 0; it < 4; ++it)
#pragma unroll
        for (int j = 0; j < 4; ++j)
          acc2[it][j] = __builtin_amdgcn_mfma_f32_16x16x32_f16(av[it], bfr[j], acc2[it][j], 0, 0, 0);
    }
  }

  // ---- store: 64 rows x 64 cols (cols w*64 + c*4 + j), float4 nt-stores ----
  const f32x4 b24 = *(const f32x4*)(pb2 + w * 64 + c * 4);
#pragma unroll
  for (int it = 0; it < 4; ++it)
#pragma unroll
    for (int r = 0; r < 4; ++r) {
      const int grow = rowbase + it * 16 + q * 4 + r;
      f32x4 st;
#pragma unroll
      for (int j = 0; j < 4; ++j) st[j] = acc2[it][j][r] + b24[j];
      __builtin_nontemporal_store(st, (f32x4*)(out + grow * 256 + w * 64 + c * 4));
    }
}

extern "C" void kernel_launch(void* const* d_in, const int* in_sizes, int n_in,
                              void* d_out, int out_size, void* d_ws, size_t ws_size,
                              hipStream_t stream) {
  (void)in_sizes; (void)n_in; (void)out_size; (void)ws_size;
  const float* f0 = (const float*)d_in[0];
  const int* phone = (const int*)d_in[1];
  const float* dur = (const float*)d_in[2];
  const int* midi = (const int*)d_in[3];
  const float* f0_w1 = (const float*)d_in[4];
  const float* f0_b1 = (const float*)d_in[5];
  const float* f0_w2 = (const float*)d_in[6];
  const float* f0_b2 = (const float*)d_in[7];
  const float* ptab = (const float*)d_in[8];
  const float* mtab = (const float*)d_in[9];
  const float* dur_w1 = (const float*)d_in[10];
  const float* dur_b1 = (const float*)d_in[11];
  const float* dur_w2 = (const float*)d_in[12];
  const float* dur_b2 = (const float*)d_in[13];
  const float* W1 = (const float*)d_in[14];
  const float* pb1 = (const float*)d_in[15];
  const float* ln_g = (const float*)d_in[16];
  const float* ln_b = (const float*)d_in[17];
  const float* W2 = (const float*)d_in[18];
  const float* pb2 = (const float*)d_in[19];
  char* ws = (char*)d_ws;
  float* out = (float*)d_out;

  prep_tables<<<293, 1024, 0, stream>>>(f0_w2, f0_b2, ptab, mtab, dur_w2, dur_b2, W1, pb1, (float*)ws);
  prep_frags<<<160, 64, 0, stream>>>(W2, ws);
  cond_enc_main<<<NBLK, 256, 0, stream>>>(f0, phone, dur, midi, f0_w1, f0_b1, dur_w1, dur_b1,
                                          ln_g, ln_b, pb2, ws, out);
}